// Round 3
// baseline (1363.174 us; speedup 1.0000x reference)
//
#include <hip/hip_runtime.h>
#include <hip/hip_bf16.h>
#include <stdint.h>

typedef unsigned short u16;
typedef unsigned int   u32;
typedef __attribute__((ext_vector_type(4))) float f32x4;
typedef __attribute__((ext_vector_type(2))) float f32x2;
typedef __attribute__((ext_vector_type(8))) short s16x8;

#define DEV __device__ __forceinline__

static constexpr int EDIM  = 1024;
static constexpr int MROWS = 8 * 48 * 48;   // 18432
static constexpr int MT256 = MROWS / 256;   // 72 m-tiles

DEV float b2f(u16 x) { u32 u = ((u32)x) << 16; float f; __builtin_memcpy(&f, &u, 4); return f; }
DEV u16 f2b(float f) {
    u32 u; __builtin_memcpy(&u, &f, 4);
    u32 r = (u + 0x7FFFu + ((u >> 16) & 1u)) >> 16;
    return (u16)r;
}

#define GLDS16(gsrc, ldst) __builtin_amdgcn_global_load_lds( \
    (const __attribute__((address_space(1))) u32*)(gsrc),    \
    (__attribute__((address_space(3))) u32*)(ldst), 16, 0, 0)

#define BAR()   __builtin_amdgcn_s_barrier()
#define LGKM0() asm volatile("s_waitcnt lgkmcnt(0)" ::: "memory")

// ---------------- weight convert+transpose: W[K][N] f32 -> Wt[N][K] bf16 ----
__global__ void wconv_kernel(const float* __restrict__ W, u16* __restrict__ Wt,
                             int K, int N) {
    __shared__ u16 tile[64][65];
    int n0 = blockIdx.x * 64, k0 = blockIdx.y * 64;
    int tx = threadIdx.x & 63, ty = threadIdx.x >> 6;
#pragma unroll
    for (int i = 0; i < 16; ++i) {
        int r = ty * 16 + i;
        tile[r][tx] = f2b(W[(size_t)(k0 + r) * N + n0 + tx]);
    }
    __syncthreads();
#pragma unroll
    for (int i = 0; i < 16; ++i) {
        int r = ty * 16 + i;
        Wt[(size_t)(n0 + r) * K + k0 + tx] = tile[tx][r];
    }
}

__global__ void bconcat_kernel(const float* __restrict__ a, const float* __restrict__ b,
                               const float* __restrict__ c, float* __restrict__ out) {
    int i = blockIdx.x * 256 + threadIdx.x;  // 3072
    out[i] = (i < 1024) ? a[i] : ((i < 2048) ? b[i - 1024] : c[i - 2048]);
}

// ---------------- gather emb f32 -> Xc bf16 in col-attn layout -------------
__global__ void gather_kernel(const float* __restrict__ emb, u16* __restrict__ Xc) {
    int gid = blockIdx.x * 256 + threadIdx.x;   // MROWS*512 total
    int r = gid >> 9, c2 = gid & 511;
    int b = r / 2304, k = (r / 48) % 48, n = r % 48;
    int src = (n * 48 + k) * 8 + b;
    f32x2 v = *(const f32x2*)&emb[(size_t)src * EDIM + c2 * 2];
    u32 p = (u32)f2b(v.x) | ((u32)f2b(v.y) << 16);
    *(u32*)&Xc[(size_t)r * EDIM + c2 * 2] = p;
}

__global__ void zero_kernel(float* __restrict__ p, int n) {
    int i = blockIdx.x * 256 + threadIdx.x;
    if (i < n) p[i] = 0.f;
}

// ================= 256x256 8-phase GEMM ====================================
// C[M][ldc] = act(A @ Bt^T + bias). BM=BN=256, BK=64, 8 waves (2Mx4N),
// wave tile 128x64. Double-buffered 128KiB LDS, counted vmcnt(6).
// LDS swizzle: within each 64B half-row, 16B granule g stored at (g+(row>>1))&3.
// A-half h = 64-row quads {h,h+2} (bit6); B-half h = 32-row stripes (bit5)==h.
DEV s16x8 ldsrd(const u16* lds, int r, int kk, int qq) {
    return *(const s16x8*)&lds[r * 64 + kk * 32 + (((qq + (r >> 1)) & 3) << 3)];
}

DEV void stage_tileA(u16* lds, const u16* Ag, int lda, int m0, int ka,
                     int h, int wv, int lane) {
#pragma unroll
    for (int i = 0; i < 2; ++i) {
        int blk  = wv * 2 + i;                                // 0..15, 8 rows each
        int row0 = (h + 2 * (blk >> 3)) * 64 + (blk & 7) * 8; // wave-uniform
        int rr   = row0 + (lane >> 3);
        int pg   = lane & 7;
        int qq   = ((pg & 3) - (rr >> 1)) & 3;                // inverse swizzle
        const u16* g = Ag + (size_t)(m0 + rr) * lda + ka + (pg >> 2) * 32 + qq * 8;
        GLDS16(g, lds + row0 * 64);
    }
}

DEV void stage_tileB(u16* lds, const u16* Bg, int ldb, int n0, int kb,
                     int h, int wv, int lane) {
#pragma unroll
    for (int i = 0; i < 2; ++i) {
        int blk  = wv * 2 + i;
        int row0 = (blk >> 2) * 64 + h * 32 + (blk & 3) * 8;  // wave-uniform
        int rr   = row0 + (lane >> 3);
        int pg   = lane & 7;
        int qq   = ((pg & 3) - (rr >> 1)) & 3;
        const u16* g = Bg + (size_t)(n0 + rr) * ldb + kb + (pg >> 2) * 32 + qq * 8;
        GLDS16(g, lds + row0 * 64);
    }
}

template<int KTOT, bool DUALA, bool TANH, bool PERM, bool SCORE, bool WRC, int OMAP>
__global__ __launch_bounds__(512, 2) void gemm256_kernel(
    const u16* __restrict__ A1, const u16* __restrict__ A2, int lda,
    const u16* __restrict__ Bt, const float* __restrict__ bias,
    u16* __restrict__ C, int ldc, float* __restrict__ outF,
    const float* __restrict__ w2, float* __restrict__ score) {
    __shared__ u16 lA[2][256 * 64];
    __shared__ u16 lB[2][256 * 64];
    constexpr int NT = KTOT / 64;

    int bid = blockIdx.x;
    int mt = bid % MT256, nt = bid / MT256;   // 72%8==0 -> same-mt blocks same XCD
    int m0 = mt * 256, n0 = nt * 256;
    int tid = threadIdx.x, lane = tid & 63, wv = tid >> 6;
    int wm = wv >> 2, wn = wv & 3;            // 2 x 4 waves
    int fr = lane & 15, qq = lane >> 4;

    auto Asel = [&](int ts, const u16*& Ag, int& ka) {
        ka = ts * 64; Ag = A1;
        if (DUALA && ka >= 1024) { Ag = A2; ka -= 1024; }
    };

    f32x4 acc[8][4];
#pragma unroll
    for (int i = 0; i < 8; ++i)
#pragma unroll
        for (int j = 0; j < 4; ++j) acc[i][j] = (f32x4)0.f;

    // ---- prologue: t0 all 4 halves -> buf0; t1 {Ah0,Bh0,Bh1} -> buf1 ----
    {
        const u16* Ag; int ka; Asel(0, Ag, ka);
        stage_tileA(&lA[0][0], Ag, lda, m0, ka, 0, wv, lane);
        stage_tileA(&lA[0][0], Ag, lda, m0, ka, 1, wv, lane);
        stage_tileB(&lB[0][0], Bt, KTOT, n0, 0, 0, wv, lane);
        stage_tileB(&lB[0][0], Bt, KTOT, n0, 0, 1, wv, lane);
    }
    if (NT > 1) {
        const u16* Ag; int ka; Asel(1, Ag, ka);
        stage_tileA(&lA[1][0], Ag, lda, m0, ka, 0, wv, lane);
        stage_tileB(&lB[1][0], Bt, KTOT, n0, 64, 0, wv, lane);
        stage_tileB(&lB[1][0], Bt, KTOT, n0, 64, 1, wv, lane);
    }
    asm volatile("s_waitcnt vmcnt(6)" ::: "memory");  // t0's 8 loads landed
    BAR();

    s16x8 A8[8], B0[4], B1[4];

    for (int t = 0; t < NT; ++t) {
        int buf = t & 1;
        const u16* lAb = &lA[buf][0];
        const u16* lBb = &lB[buf][0];

        // ---- phase 0: read A-h0 + B-h0; stage Ah1(t+1) -> other buf ----
#pragma unroll
        for (int m = 0; m < 4; ++m)
#pragma unroll
            for (int kk = 0; kk < 2; ++kk)
                A8[m * 2 + kk] = ldsrd(lAb, wm * 128 + m * 16 + fr, kk, qq);
#pragma unroll
        for (int n = 0; n < 2; ++n)
#pragma unroll
            for (int kk = 0; kk < 2; ++kk)
                B0[n * 2 + kk] = ldsrd(lBb, wn * 64 + n * 16 + fr, kk, qq);
        if (t + 1 < NT) {
            const u16* Ag; int ka; Asel(t + 1, Ag, ka);
            stage_tileA(&lA[buf ^ 1][0], Ag, lda, m0, ka, 1, wv, lane);
        }
        BAR(); LGKM0();
        __builtin_amdgcn_s_setprio(1);
#pragma unroll
        for (int m = 0; m < 4; ++m)
#pragma unroll
            for (int n = 0; n < 2; ++n)
#pragma unroll
                for (int kk = 0; kk < 2; ++kk)
                    acc[m][n] = __builtin_amdgcn_mfma_f32_16x16x32_bf16(
                        A8[m * 2 + kk], B0[n * 2 + kk], acc[m][n], 0, 0, 0);
        __builtin_amdgcn_s_setprio(0);
        BAR();

        // ---- phase 1: read B-h1; stage Ah0(t+2) -> this buf ----
#pragma unroll
        for (int n = 0; n < 2; ++n)
#pragma unroll
            for (int kk = 0; kk < 2; ++kk)
                B1[n * 2 + kk] = ldsrd(lBb, wn * 64 + 32 + n * 16 + fr, kk, qq);
        if (t + 2 < NT) {
            const u16* Ag; int ka; Asel(t + 2, Ag, ka);
            stage_tileA(&lA[buf][0], Ag, lda, m0, ka, 0, wv, lane);
        }
        BAR(); LGKM0();
        __builtin_amdgcn_s_setprio(1);
#pragma unroll
        for (int m = 0; m < 4; ++m)
#pragma unroll
            for (int n = 0; n < 2; ++n)
#pragma unroll
                for (int kk = 0; kk < 2; ++kk)
                    acc[m][n + 2] = __builtin_amdgcn_mfma_f32_16x16x32_bf16(
                        A8[m * 2 + kk], B1[n * 2 + kk], acc[m][n + 2], 0, 0, 0);
        __builtin_amdgcn_s_setprio(0);
        BAR();

        // ---- phase 2: read A-h1; stage Bh0(t+2) ----
#pragma unroll
        for (int m = 0; m < 4; ++m)
#pragma unroll
            for (int kk = 0; kk < 2; ++kk)
                A8[m * 2 + kk] = ldsrd(lAb, wm * 128 + 64 + m * 16 + fr, kk, qq);
        if (t + 2 < NT)
            stage_tileB(&lB[buf][0], Bt, KTOT, n0, (t + 2) * 64, 0, wv, lane);
        BAR(); LGKM0();
        __builtin_amdgcn_s_setprio(1);
#pragma unroll
        for (int m = 0; m < 4; ++m)
#pragma unroll
            for (int n = 0; n < 2; ++n)
#pragma unroll
                for (int kk = 0; kk < 2; ++kk)
                    acc[m + 4][n] = __builtin_amdgcn_mfma_f32_16x16x32_bf16(
                        A8[m * 2 + kk], B0[n * 2 + kk], acc[m + 4][n], 0, 0, 0);
        __builtin_amdgcn_s_setprio(0);
        BAR();

        // ---- phase 3: stage Bh1(t+2); MFMA; counted vmcnt ----
        if (t + 2 < NT)
            stage_tileB(&lB[buf][0], Bt, KTOT, n0, (t + 2) * 64, 1, wv, lane);
        __builtin_amdgcn_s_setprio(1);
#pragma unroll
        for (int m = 0; m < 4; ++m)
#pragma unroll
            for (int n = 0; n < 2; ++n)
#pragma unroll
                for (int kk = 0; kk < 2; ++kk)
                    acc[m + 4][n + 2] = __builtin_amdgcn_mfma_f32_16x16x32_bf16(
                        A8[m * 2 + kk], B1[n * 2 + kk], acc[m + 4][n + 2], 0, 0, 0);
        __builtin_amdgcn_s_setprio(0);
        if (t < NT - 2)       asm volatile("s_waitcnt vmcnt(6)" ::: "memory");
        else if (t == NT - 2) asm volatile("s_waitcnt vmcnt(0)" ::: "memory");
        BAR();
    }

    // ---- epilogue ----
    int crow4 = qq * 4;
#pragma unroll
    for (int mf = 0; mf < 8; ++mf) {
#pragma unroll
        for (int j = 0; j < 4; ++j) {
            int row = m0 + wm * 128 + mf * 16 + crow4 + j;
            int orow = row;
            int o32 = 0;
            if (PERM || OMAP == 1) {  // rows are (b,k,n)
                int b = row / 2304, k = (row / 48) % 48, n = row % 48;
                if (PERM) orow = (b * 48 + n) * 48 + k;
                if (OMAP == 1) o32 = k * 384 + b * 48 + n;
            }
            if (OMAP == 2) {          // rows are (b,n,k)
                int b = row / 2304, n = (row / 48) % 48, k = row % 48;
                o32 = k * 384 + b * 48 + n;
            }
            float sc_part = 0.f;
#pragma unroll
            for (int nf = 0; nf < 4; ++nf) {
                int col = n0 + wn * 64 + nf * 16 + fr;
                float v = acc[mf][nf][j];
                if (bias) v += bias[col];
                if (TANH) v = tanhf(v);
                if (WRC) C[(size_t)orow * ldc + col] = f2b(v);
                if (OMAP) outF[(size_t)o32 * EDIM + col] = v;
                if (SCORE) sc_part += v * w2[col];
            }
            if (SCORE) {
                sc_part += __shfl_xor(sc_part, 1);
                sc_part += __shfl_xor(sc_part, 2);
                sc_part += __shfl_xor(sc_part, 4);
                sc_part += __shfl_xor(sc_part, 8);
                if (fr == 0) atomicAdd(&score[row], sc_part);
            }
        }
    }
}

// ---------------- attention: 48x48, dh=128, no mask, in-place O -> Q cols --
__global__ __launch_bounds__(64) void attn_kernel(u16* __restrict__ QKV) {
    __shared__ u16 lVt[128 * 72];
    __shared__ u16 lP[48 * 72];
    const int LDQ = 3072;
    int bb = blockIdx.x >> 3, h = blockIdx.x & 7;
    int lane = threadIdx.x;
    u16* Qp = QKV + (size_t)bb * 48 * LDQ + h * 128;
    const u16* Kp = Qp + 1024;
    const u16* Vp = Qp + 2048;

#pragma unroll
    for (int i = 0; i < 48; ++i) {
        u32 vv = *(const u32*)&Vp[(size_t)i * LDQ + lane * 2];
        lVt[(lane * 2) * 72 + i]     = (u16)(vv & 0xffffu);
        lVt[(lane * 2 + 1) * 72 + i] = (u16)(vv >> 16);
    }
    for (int i = lane; i < 128 * 16; i += 64) { int d = i >> 4, c = 48 + (i & 15); lVt[d * 72 + c] = 0; }
    for (int i = lane; i < 48 * 16; i += 64)  { int t = i >> 4, c = 48 + (i & 15); lP[t * 72 + c] = 0; }
    __syncthreads();

    int fr = lane & 15, fk = (lane >> 4) * 8, crow4 = (lane >> 4) * 4;
    f32x4 sc[3][3];
#pragma unroll
    for (int mf = 0; mf < 3; ++mf)
#pragma unroll
        for (int nf = 0; nf < 3; ++nf) sc[mf][nf] = (f32x4)0.f;

#pragma unroll
    for (int kk = 0; kk < 4; ++kk) {
        s16x8 aq[3], bk[3];
#pragma unroll
        for (int mf = 0; mf < 3; ++mf) aq[mf] = *(const s16x8*)&Qp[(size_t)(mf * 16 + fr) * LDQ + kk * 32 + fk];
#pragma unroll
        for (int nf = 0; nf < 3; ++nf) bk[nf] = *(const s16x8*)&Kp[(size_t)(nf * 16 + fr) * LDQ + kk * 32 + fk];
#pragma unroll
        for (int mf = 0; mf < 3; ++mf)
#pragma unroll
            for (int nf = 0; nf < 3; ++nf)
                sc[mf][nf] = __builtin_amdgcn_mfma_f32_16x16x32_bf16(aq[mf], bk[nf], sc[mf][nf], 0, 0, 0);
    }

    const float scale = 0.08838834764831845f;  // 1/sqrt(128)
#pragma unroll
    for (int mf = 0; mf < 3; ++mf) {
#pragma unroll
        for (int j = 0; j < 4; ++j) {
            float v0 = sc[mf][0][j] * scale;
            float v1 = sc[mf][1][j] * scale;
            float v2 = sc[mf][2][j] * scale;
            float mx = fmaxf(v0, fmaxf(v1, v2));
            mx = fmaxf(mx, __shfl_xor(mx, 1));
            mx = fmaxf(mx, __shfl_xor(mx, 2));
            mx = fmaxf(mx, __shfl_xor(mx, 4));
            mx = fmaxf(mx, __shfl_xor(mx, 8));
            float e0 = __expf(v0 - mx), e1 = __expf(v1 - mx), e2 = __expf(v2 - mx);
            float s = e0 + e1 + e2;
            s += __shfl_xor(s, 1);
            s += __shfl_xor(s, 2);
            s += __shfl_xor(s, 4);
            s += __shfl_xor(s, 8);
            float inv = 1.f / s;
            int t = mf * 16 + crow4 + j;
            lP[t * 72 + 0  + fr] = f2b(e0 * inv);
            lP[t * 72 + 16 + fr] = f2b(e1 * inv);
            lP[t * 72 + 32 + fr] = f2b(e2 * inv);
        }
    }
    __syncthreads();

    f32x4 o[3][8];
#pragma unroll
    for (int mf = 0; mf < 3; ++mf)
#pragma unroll
        for (int nf = 0; nf < 8; ++nf) o[mf][nf] = (f32x4)0.f;

#pragma unroll
    for (int kk = 0; kk < 2; ++kk) {
        s16x8 ap[3];
#pragma unroll
        for (int mf = 0; mf < 3; ++mf) ap[mf] = *(const s16x8*)&lP[(mf * 16 + fr) * 72 + kk * 32 + fk];
#pragma unroll
        for (int nf = 0; nf < 8; ++nf) {
            s16x8 bv = *(const s16x8*)&lVt[(nf * 16 + fr) * 72 + kk * 32 + fk];
#pragma unroll
            for (int mf = 0; mf < 3; ++mf)
                o[mf][nf] = __builtin_amdgcn_mfma_f32_16x16x32_bf16(ap[mf], bv, o[mf][nf], 0, 0, 0);
        }
    }
#pragma unroll
    for (int mf = 0; mf < 3; ++mf)
#pragma unroll
        for (int nf = 0; nf < 8; ++nf)
#pragma unroll
            for (int j = 0; j < 4; ++j) {
                int t = mf * 16 + crow4 + j, d = nf * 16 + fr;
                Qp[(size_t)t * LDQ + d] = f2b(o[mf][nf][j]);
            }
}

// ---------------- combine (memory_bank only) --------------------------------
__global__ void combine_kernel(const u16* __restrict__ RDR, const u16* __restrict__ CDR,
                               const float* __restrict__ srow, const float* __restrict__ scol,
                               const float* __restrict__ emb, float* __restrict__ out_mb) {
    int o = blockIdx.x;
    int k = o / 384, b = (o / 48) & 7, n = o % 48;
    int r2 = (b * 48 + n) * 48 + k;
    float rs = srow[r2], cs = scol[r2];
    float m = fmaxf(rs, cs);
    float e0 = __expf(rs - m), e1 = __expf(cs - m);
    float inv = 1.f / (e0 + e1);
    float w0 = e0 * inv, w1 = e1 * inv;
    const size_t rb = (size_t)r2 * EDIM;
    const size_t ob = (size_t)o * EDIM;
    const size_t eb = ((size_t)(n * 48 + k) * 8 + b) * EDIM;
    for (int e = threadIdx.x; e < EDIM; e += 256) {
        float rv = b2f(RDR[rb + e]);
        float cv = b2f(CDR[rb + e]);
        out_mb[ob + e] = w0 * rv + w1 * cv + emb[eb + e];
    }
}

__global__ void mean_kernel(const float* __restrict__ mb, float* __restrict__ out0) {
    int idx = blockIdx.x * 256 + threadIdx.x;  // 393216
    int n = idx >> 13, b = (idx >> 10) & 7, e = idx & 1023;
    float s = 0.f;
#pragma unroll 8
    for (int k = 0; k < 48; ++k) s += mb[((size_t)(k * 384 + b * 48 + n)) * EDIM + e];
    out0[idx] = s * (1.f / 48.f);
}

// ---------------------------------------------------------------------------
extern "C" void kernel_launch(void* const* d_in, const int* in_sizes, int n_in,
                              void* d_out, int out_size, void* d_ws, size_t ws_size,
                              hipStream_t stream) {
    const float* emb    = (const float*)d_in[0];
    const float* Wq_c   = (const float*)d_in[1];
    const float* bq_c   = (const float*)d_in[2];
    const float* Wk_c   = (const float*)d_in[3];
    const float* bk_c   = (const float*)d_in[4];
    const float* Wv_c   = (const float*)d_in[5];
    const float* bv_c   = (const float*)d_in[6];
    const float* Wo_c   = (const float*)d_in[7];
    const float* bo_c   = (const float*)d_in[8];
    const float* Wq_r   = (const float*)d_in[9];
    const float* bq_r   = (const float*)d_in[10];
    const float* Wk_r   = (const float*)d_in[11];
    const float* bk_r   = (const float*)d_in[12];
    const float* Wv_r   = (const float*)d_in[13];
    const float* bv_r   = (const float*)d_in[14];
    const float* Wo_r   = (const float*)d_in[15];
    const float* bo_r   = (const float*)d_in[16];
    const float* W_gen  = (const float*)d_in[17];
    const float* W_mlp1 = (const float*)d_in[18];
    const float* W_mlp2 = (const float*)d_in[19];

    char* ws = (char*)d_ws;
    size_t off = 0;
    auto alloc = [&](size_t bytes) { char* p = ws + off; off += (bytes + 255) & ~(size_t)255; return p; };
    u16*   WqkvC = (u16*)alloc((size_t)3072 * 1024 * 2);
    u16*   WqkvR = (u16*)alloc((size_t)3072 * 1024 * 2);
    u16*   WoC   = (u16*)alloc((size_t)1024 * 1024 * 2);
    u16*   WoR   = (u16*)alloc((size_t)1024 * 1024 * 2);
    u16*   WgT   = (u16*)alloc((size_t)1024 * 2048 * 2);
    u16*   W1T   = (u16*)alloc((size_t)1024 * 2048 * 2);
    float* bqkvC = (float*)alloc(3072 * 4);
    float* bqkvR = (float*)alloc(3072 * 4);
    u16*   XA    = (u16*)alloc((size_t)MROWS * 1024 * 2);   // gather input; later GEN
    u16*   QKV   = (u16*)alloc((size_t)MROWS * 3072 * 2);   // fused QKV, O in-place
    u16*   CDR   = (u16*)alloc((size_t)MROWS * 1024 * 2);
    u16*   RDR   = (u16*)alloc((size_t)MROWS * 1024 * 2);
    float* score_row = (float*)alloc((size_t)MROWS * 4);
    float* score_col = (float*)alloc((size_t)MROWS * 4);
    (void)ws_size; (void)in_sizes; (void)n_in; (void)out_size;

    dim3 tb(256);
    wconv_kernel<<<dim3(16, 16), tb, 0, stream>>>(Wq_c, WqkvC,                   1024, 1024);
    wconv_kernel<<<dim3(16, 16), tb, 0, stream>>>(Wk_c, WqkvC + 1024 * 1024,     1024, 1024);
    wconv_kernel<<<dim3(16, 16), tb, 0, stream>>>(Wv_c, WqkvC + 2 * 1024 * 1024, 1024, 1024);
    wconv_kernel<<<dim3(16, 16), tb, 0, stream>>>(Wo_c, WoC,                     1024, 1024);
    wconv_kernel<<<dim3(16, 16), tb, 0, stream>>>(Wq_r, WqkvR,                   1024, 1024);
    wconv_kernel<<<dim3(16, 16), tb, 0, stream>>>(Wk_r, WqkvR + 1024 * 1024,     1024, 1024);
    wconv_kernel<<<dim3(16, 16), tb, 0, stream>>>(Wv_r, WqkvR + 2 * 1024 * 1024, 1024, 1024);
    wconv_kernel<<<dim3(16, 16), tb, 0, stream>>>(Wo_r, WoR,                     1024, 1024);
    wconv_kernel<<<dim3(16, 32), tb, 0, stream>>>(W_gen,  WgT, 2048, 1024);
    wconv_kernel<<<dim3(16, 32), tb, 0, stream>>>(W_mlp1, W1T, 2048, 1024);
    bconcat_kernel<<<12, tb, 0, stream>>>(bq_c, bk_c, bv_c, bqkvC);
    bconcat_kernel<<<12, tb, 0, stream>>>(bq_r, bk_r, bv_r, bqkvR);

    gather_kernel<<<MROWS * 512 / 256, tb, 0, stream>>>(emb, XA);
    zero_kernel<<<(2 * MROWS + 255) / 256, tb, 0, stream>>>(score_row, 2 * MROWS);

    float* out = (float*)d_out;
    float* out_mb  = out + 393216;
    float* out_col = out + 393216 + 18874368;
    float* out_row = out + 393216 + 2 * 18874368;

    dim3 tb512(512);
    const int G12 = MT256 * 12, G4 = MT256 * 4;   // 864, 288
    // col QKV (fused, N=3072)
    gemm256_kernel<1024, false, false, false, false, true, 0><<<G12, tb512, 0, stream>>>(
        XA, nullptr, 1024, WqkvC, bqkvC, QKV, 3072, nullptr, nullptr, nullptr);
    attn_kernel<<<384 * 8, 64, 0, stream>>>(QKV);
    // col out-proj: rows (b,k,n) -> CDR rows (b,n,k); f32 out_col
    gemm256_kernel<1024, false, false, true, false, true, 1><<<G4, tb512, 0, stream>>>(
        QKV, nullptr, 3072, WoC, bo_c, CDR, 1024, out_col, nullptr, nullptr);
    // row QKV
    gemm256_kernel<1024, false, false, false, false, true, 0><<<G12, tb512, 0, stream>>>(
        CDR, nullptr, 1024, WqkvR, bqkvR, QKV, 3072, nullptr, nullptr, nullptr);
    attn_kernel<<<384 * 8, 64, 0, stream>>>(QKV);
    // row out-proj: rows (b,n,k) -> RDR; f32 out_row
    gemm256_kernel<1024, false, false, false, false, true, 2><<<G4, tb512, 0, stream>>>(
        QKV, nullptr, 3072, WoR, bo_r, RDR, 1024, out_row, nullptr, nullptr);
    // gen = tanh(concat(RDR,CDR) @ W_gen) -> XA (reused as GEN)
    gemm256_kernel<2048, true, true, false, false, true, 0><<<G4, tb512, 0, stream>>>(
        RDR, CDR, 1024, WgT, nullptr, XA, 1024, nullptr, nullptr, nullptr);
    // scores
    gemm256_kernel<2048, true, true, false, true, false, 0><<<G4, tb512, 0, stream>>>(
        RDR, XA, 1024, W1T, nullptr, nullptr, 1024, nullptr, W_mlp2, score_row);
    gemm256_kernel<2048, true, true, false, true, false, 0><<<G4, tb512, 0, stream>>>(
        CDR, XA, 1024, W1T, nullptr, nullptr, 1024, nullptr, W_mlp2, score_col);

    combine_kernel<<<MROWS, tb, 0, stream>>>(RDR, CDR, score_row, score_col, emb, out_mb);
    mean_kernel<<<393216 / 256, tb, 0, stream>>>(out_mb, out);
}

// Round 4
// 1202.585 us; speedup vs baseline: 1.1335x; 1.1335x over previous
//
#include <hip/hip_runtime.h>
#include <hip/hip_bf16.h>
#include <stdint.h>

typedef unsigned short u16;
typedef unsigned int   u32;
typedef __attribute__((ext_vector_type(4))) float f32x4;
typedef __attribute__((ext_vector_type(2))) float f32x2;
typedef __attribute__((ext_vector_type(8))) short s16x8;

#define DEV __device__ __forceinline__

static constexpr int EDIM  = 1024;
static constexpr int MROWS = 8 * 48 * 48;   // 18432
static constexpr int MT256 = MROWS / 256;   // 72 m-tiles

DEV float b2f(u16 x) { u32 u = ((u32)x) << 16; float f; __builtin_memcpy(&f, &u, 4); return f; }
DEV u16 f2b(float f) {
    u32 u; __builtin_memcpy(&u, &f, 4);
    u32 r = (u + 0x7FFFu + ((u >> 16) & 1u)) >> 16;
    return (u16)r;
}

#define GLDS16(gsrc, ldst) __builtin_amdgcn_global_load_lds( \
    (const __attribute__((address_space(1))) u32*)(gsrc),    \
    (__attribute__((address_space(3))) u32*)(ldst), 16, 0, 0)

#define BAR()   __builtin_amdgcn_s_barrier()
#define LGKM0() asm volatile("s_waitcnt lgkmcnt(0)" ::: "memory")

// ---------------- weight convert+transpose: W[K][N] f32 -> Wt[N][K] bf16 ----
__global__ void wconv_kernel(const float* __restrict__ W, u16* __restrict__ Wt,
                             int K, int N) {
    __shared__ u16 tile[64][65];
    int n0 = blockIdx.x * 64, k0 = blockIdx.y * 64;
    int tx = threadIdx.x & 63, ty = threadIdx.x >> 6;
#pragma unroll
    for (int i = 0; i < 16; ++i) {
        int r = ty * 16 + i;
        tile[r][tx] = f2b(W[(size_t)(k0 + r) * N + n0 + tx]);
    }
    __syncthreads();
#pragma unroll
    for (int i = 0; i < 16; ++i) {
        int r = ty * 16 + i;
        Wt[(size_t)(n0 + r) * K + k0 + tx] = tile[tx][r];
    }
}

__global__ void bconcat_kernel(const float* __restrict__ a, const float* __restrict__ b,
                               const float* __restrict__ c, float* __restrict__ out) {
    int i = blockIdx.x * 256 + threadIdx.x;  // 3072
    out[i] = (i < 1024) ? a[i] : ((i < 2048) ? b[i - 1024] : c[i - 2048]);
}

// ---------------- gather emb f32 -> Xc bf16 in col-attn layout -------------
__global__ void gather_kernel(const float* __restrict__ emb, u16* __restrict__ Xc) {
    int gid = blockIdx.x * 256 + threadIdx.x;   // MROWS*512 total
    int r = gid >> 9, c2 = gid & 511;
    int b = r / 2304, k = (r / 48) % 48, n = r % 48;
    int src = (n * 48 + k) * 8 + b;
    f32x2 v = *(const f32x2*)&emb[(size_t)src * EDIM + c2 * 2];
    u32 p = (u32)f2b(v.x) | ((u32)f2b(v.y) << 16);
    *(u32*)&Xc[(size_t)r * EDIM + c2 * 2] = p;
}

__global__ void zero_kernel(float* __restrict__ p, int n) {
    int i = blockIdx.x * 256 + threadIdx.x;
    if (i < n) p[i] = 0.f;
}

// ================= 256x256 8-phase GEMM ====================================
// C[M][ldc] = act(A @ Bt^T + bias). BM=BN=256, BK=64, 8 waves (2Mx4N),
// wave tile 128x64. Double-buffered 128KiB LDS, counted vmcnt(6).
// LDS swizzle: row = 128B = 8 granules of 16B; logical granule gl of row r
// stored at physical granule gl ^ (r&7). Conflict-free: any 8 consecutive
// lanes of ds_read_b128 (same gl, r&7 = 0..7) hit 8 distinct granule columns.
DEV s16x8 ldsrd(const u16* lds, int r, int kk, int qq) {
    int gl = kk * 4 + qq;
    return *(const s16x8*)&lds[r * 64 + ((gl ^ (r & 7)) << 3)];
}

DEV void stage_tileA(u16* lds, const u16* Ag, int lda, int m0, int ka,
                     int h, int wv, int lane) {
#pragma unroll
    for (int i = 0; i < 2; ++i) {
        int blk  = wv * 2 + i;                                // 0..15, 8 rows each
        int row0 = (h + 2 * (blk >> 3)) * 64 + (blk & 7) * 8; // wave-uniform
        int rr   = row0 + (lane >> 3);
        int gl   = (lane & 7) ^ (rr & 7);                     // inverse swizzle
        const u16* g = Ag + (size_t)(m0 + rr) * lda + ka + gl * 8;
        GLDS16(g, lds + row0 * 64);
    }
}

DEV void stage_tileB(u16* lds, const u16* Bg, int ldb, int n0, int kb,
                     int h, int wv, int lane) {
#pragma unroll
    for (int i = 0; i < 2; ++i) {
        int blk  = wv * 2 + i;
        int row0 = (blk >> 2) * 64 + h * 32 + (blk & 3) * 8;  // wave-uniform
        int rr   = row0 + (lane >> 3);
        int gl   = (lane & 7) ^ (rr & 7);
        const u16* g = Bg + (size_t)(n0 + rr) * ldb + kb + gl * 8;
        GLDS16(g, lds + row0 * 64);
    }
}

template<int KTOT, bool DUALA, bool TANH, bool PERM, bool SCORE, bool WRC, int OMAP, bool MERGE2>
__global__ __launch_bounds__(512, 2) void gemm256_kernel(
    const u16* __restrict__ A1, const u16* __restrict__ A1b,
    const u16* __restrict__ A2, int lda,
    const u16* __restrict__ Bt, const float* __restrict__ bias,
    u16* __restrict__ C, int ldc, float* __restrict__ outF,
    const float* __restrict__ w2, float* __restrict__ score,
    float* __restrict__ scoreb) {
    __shared__ u16 lA[2][256 * 64];
    __shared__ u16 lB[2][256 * 64];
    constexpr int NT = KTOT / 64;

    int bid = blockIdx.x;
    if (MERGE2 && bid >= MT256 * 4) { bid -= MT256 * 4; A1 = A1b; score = scoreb; }
    int mt = bid % MT256, nt = bid / MT256;   // 72%8==0 -> same-mt blocks same XCD
    int m0 = mt * 256, n0 = nt * 256;
    int tid = threadIdx.x, lane = tid & 63, wv = tid >> 6;
    int wm = wv >> 2, wn = wv & 3;            // 2 x 4 waves
    int fr = lane & 15, qq = lane >> 4;

    auto Asel = [&](int ts, const u16*& Ag, int& ka) {
        ka = ts * 64; Ag = A1;
        if (DUALA && ka >= 1024) { Ag = A2; ka -= 1024; }
    };

    f32x4 acc[8][4];
#pragma unroll
    for (int i = 0; i < 8; ++i)
#pragma unroll
        for (int j = 0; j < 4; ++j) acc[i][j] = (f32x4)0.f;

    // ---- prologue: t0 all 4 halves -> buf0; t1 {Ah0,Bh0,Bh1} -> buf1 ----
    {
        const u16* Ag; int ka; Asel(0, Ag, ka);
        stage_tileA(&lA[0][0], Ag, lda, m0, ka, 0, wv, lane);
        stage_tileA(&lA[0][0], Ag, lda, m0, ka, 1, wv, lane);
        stage_tileB(&lB[0][0], Bt, KTOT, n0, 0, 0, wv, lane);
        stage_tileB(&lB[0][0], Bt, KTOT, n0, 0, 1, wv, lane);
    }
    if (NT > 1) {
        const u16* Ag; int ka; Asel(1, Ag, ka);
        stage_tileA(&lA[1][0], Ag, lda, m0, ka, 0, wv, lane);
        stage_tileB(&lB[1][0], Bt, KTOT, n0, 64, 0, wv, lane);
        stage_tileB(&lB[1][0], Bt, KTOT, n0, 64, 1, wv, lane);
    }
    asm volatile("s_waitcnt vmcnt(6)" ::: "memory");  // t0's 8 loads landed
    BAR();

    s16x8 A8[8], B0[4], B1[4];

    for (int t = 0; t < NT; ++t) {
        int buf = t & 1;
        const u16* lAb = &lA[buf][0];
        const u16* lBb = &lB[buf][0];

        // ---- phase 0: read A-h0 + B-h0; stage Ah1(t+1) -> other buf ----
#pragma unroll
        for (int m = 0; m < 4; ++m)
#pragma unroll
            for (int kk = 0; kk < 2; ++kk)
                A8[m * 2 + kk] = ldsrd(lAb, wm * 128 + m * 16 + fr, kk, qq);
#pragma unroll
        for (int n = 0; n < 2; ++n)
#pragma unroll
            for (int kk = 0; kk < 2; ++kk)
                B0[n * 2 + kk] = ldsrd(lBb, wn * 64 + n * 16 + fr, kk, qq);
        if (t + 1 < NT) {
            const u16* Ag; int ka; Asel(t + 1, Ag, ka);
            stage_tileA(&lA[buf ^ 1][0], Ag, lda, m0, ka, 1, wv, lane);
        }
        BAR(); LGKM0();
        __builtin_amdgcn_s_setprio(1);
#pragma unroll
        for (int m = 0; m < 4; ++m)
#pragma unroll
            for (int n = 0; n < 2; ++n)
#pragma unroll
                for (int kk = 0; kk < 2; ++kk)
                    acc[m][n] = __builtin_amdgcn_mfma_f32_16x16x32_bf16(
                        A8[m * 2 + kk], B0[n * 2 + kk], acc[m][n], 0, 0, 0);
        __builtin_amdgcn_s_setprio(0);
        BAR();

        // ---- phase 1: read B-h1; stage Ah0(t+2) -> this buf ----
#pragma unroll
        for (int n = 0; n < 2; ++n)
#pragma unroll
            for (int kk = 0; kk < 2; ++kk)
                B1[n * 2 + kk] = ldsrd(lBb, wn * 64 + 32 + n * 16 + fr, kk, qq);
        if (t + 2 < NT) {
            const u16* Ag; int ka; Asel(t + 2, Ag, ka);
            stage_tileA(&lA[buf][0], Ag, lda, m0, ka, 0, wv, lane);
        }
        BAR(); LGKM0();
        __builtin_amdgcn_s_setprio(1);
#pragma unroll
        for (int m = 0; m < 4; ++m)
#pragma unroll
            for (int n = 0; n < 2; ++n)
#pragma unroll
                for (int kk = 0; kk < 2; ++kk)
                    acc[m][n + 2] = __builtin_amdgcn_mfma_f32_16x16x32_bf16(
                        A8[m * 2 + kk], B1[n * 2 + kk], acc[m][n + 2], 0, 0, 0);
        __builtin_amdgcn_s_setprio(0);
        BAR();

        // ---- phase 2: read A-h1; stage Bh0(t+2) ----
#pragma unroll
        for (int m = 0; m < 4; ++m)
#pragma unroll
            for (int kk = 0; kk < 2; ++kk)
                A8[m * 2 + kk] = ldsrd(lAb, wm * 128 + 64 + m * 16 + fr, kk, qq);
        if (t + 2 < NT)
            stage_tileB(&lB[buf][0], Bt, KTOT, n0, (t + 2) * 64, 0, wv, lane);
        BAR(); LGKM0();
        __builtin_amdgcn_s_setprio(1);
#pragma unroll
        for (int m = 0; m < 4; ++m)
#pragma unroll
            for (int n = 0; n < 2; ++n)
#pragma unroll
                for (int kk = 0; kk < 2; ++kk)
                    acc[m + 4][n] = __builtin_amdgcn_mfma_f32_16x16x32_bf16(
                        A8[m * 2 + kk], B0[n * 2 + kk], acc[m + 4][n], 0, 0, 0);
        __builtin_amdgcn_s_setprio(0);
        BAR();

        // ---- phase 3: stage Bh1(t+2); MFMA; counted vmcnt ----
        if (t + 2 < NT)
            stage_tileB(&lB[buf][0], Bt, KTOT, n0, (t + 2) * 64, 1, wv, lane);
        __builtin_amdgcn_s_setprio(1);
#pragma unroll
        for (int m = 0; m < 4; ++m)
#pragma unroll
            for (int n = 0; n < 2; ++n)
#pragma unroll
                for (int kk = 0; kk < 2; ++kk)
                    acc[m + 4][n + 2] = __builtin_amdgcn_mfma_f32_16x16x32_bf16(
                        A8[m * 2 + kk], B1[n * 2 + kk], acc[m + 4][n + 2], 0, 0, 0);
        __builtin_amdgcn_s_setprio(0);
        if (t < NT - 2)       asm volatile("s_waitcnt vmcnt(6)" ::: "memory");
        else if (t == NT - 2) asm volatile("s_waitcnt vmcnt(0)" ::: "memory");
        BAR();
    }

    // ---- epilogue ----
    int crow4 = qq * 4;
#pragma unroll
    for (int mf = 0; mf < 8; ++mf) {
#pragma unroll
        for (int j = 0; j < 4; ++j) {
            int row = m0 + wm * 128 + mf * 16 + crow4 + j;
            int orow = row;
            int o32 = 0;
            if (PERM || OMAP == 1) {  // rows are (b,k,n)
                int b = row / 2304, k = (row / 48) % 48, n = row % 48;
                if (PERM) orow = (b * 48 + n) * 48 + k;
                if (OMAP == 1) o32 = k * 384 + b * 48 + n;
            }
            if (OMAP == 2) {          // rows are (b,n,k)
                int b = row / 2304, n = (row / 48) % 48, k = row % 48;
                o32 = k * 384 + b * 48 + n;
            }
            float sc_part = 0.f;
#pragma unroll
            for (int nf = 0; nf < 4; ++nf) {
                int col = n0 + wn * 64 + nf * 16 + fr;
                float v = acc[mf][nf][j];
                if (bias) v += bias[col];
                if (TANH) v = tanhf(v);
                if (WRC) C[(size_t)orow * ldc + col] = f2b(v);
                if (OMAP) outF[(size_t)o32 * EDIM + col] = v;
                if (SCORE) sc_part += v * w2[col];
            }
            if (SCORE) {
                sc_part += __shfl_xor(sc_part, 1);
                sc_part += __shfl_xor(sc_part, 2);
                sc_part += __shfl_xor(sc_part, 4);
                sc_part += __shfl_xor(sc_part, 8);
                if (fr == 0) atomicAdd(&score[row], sc_part);
            }
        }
    }
}

// ---------------- attention: 48x48, dh=128, no mask, in-place O -> Q cols --
__global__ __launch_bounds__(64) void attn_kernel(u16* __restrict__ QKV) {
    __shared__ u16 lVt[128 * 72];
    __shared__ u16 lP[48 * 72];
    const int LDQ = 3072;
    int bb = blockIdx.x >> 3, h = blockIdx.x & 7;
    int lane = threadIdx.x;
    u16* Qp = QKV + (size_t)bb * 48 * LDQ + h * 128;
    const u16* Kp = Qp + 1024;
    const u16* Vp = Qp + 2048;

#pragma unroll
    for (int i = 0; i < 48; ++i) {
        u32 vv = *(const u32*)&Vp[(size_t)i * LDQ + lane * 2];
        lVt[(lane * 2) * 72 + i]     = (u16)(vv & 0xffffu);
        lVt[(lane * 2 + 1) * 72 + i] = (u16)(vv >> 16);
    }
    for (int i = lane; i < 128 * 16; i += 64) { int d = i >> 4, c = 48 + (i & 15); lVt[d * 72 + c] = 0; }
    for (int i = lane; i < 48 * 16; i += 64)  { int t = i >> 4, c = 48 + (i & 15); lP[t * 72 + c] = 0; }
    __syncthreads();

    int fr = lane & 15, fk = (lane >> 4) * 8, crow4 = (lane >> 4) * 4;
    f32x4 sc[3][3];
#pragma unroll
    for (int mf = 0; mf < 3; ++mf)
#pragma unroll
        for (int nf = 0; nf < 3; ++nf) sc[mf][nf] = (f32x4)0.f;

#pragma unroll
    for (int kk = 0; kk < 4; ++kk) {
        s16x8 aq[3], bk[3];
#pragma unroll
        for (int mf = 0; mf < 3; ++mf) aq[mf] = *(const s16x8*)&Qp[(size_t)(mf * 16 + fr) * LDQ + kk * 32 + fk];
#pragma unroll
        for (int nf = 0; nf < 3; ++nf) bk[nf] = *(const s16x8*)&Kp[(size_t)(nf * 16 + fr) * LDQ + kk * 32 + fk];
#pragma unroll
        for (int mf = 0; mf < 3; ++mf)
#pragma unroll
            for (int nf = 0; nf < 3; ++nf)
                sc[mf][nf] = __builtin_amdgcn_mfma_f32_16x16x32_bf16(aq[mf], bk[nf], sc[mf][nf], 0, 0, 0);
    }

    const float scale = 0.08838834764831845f;  // 1/sqrt(128)
#pragma unroll
    for (int mf = 0; mf < 3; ++mf) {
#pragma unroll
        for (int j = 0; j < 4; ++j) {
            float v0 = sc[mf][0][j] * scale;
            float v1 = sc[mf][1][j] * scale;
            float v2 = sc[mf][2][j] * scale;
            float mx = fmaxf(v0, fmaxf(v1, v2));
            mx = fmaxf(mx, __shfl_xor(mx, 1));
            mx = fmaxf(mx, __shfl_xor(mx, 2));
            mx = fmaxf(mx, __shfl_xor(mx, 4));
            mx = fmaxf(mx, __shfl_xor(mx, 8));
            float e0 = __expf(v0 - mx), e1 = __expf(v1 - mx), e2 = __expf(v2 - mx);
            float s = e0 + e1 + e2;
            s += __shfl_xor(s, 1);
            s += __shfl_xor(s, 2);
            s += __shfl_xor(s, 4);
            s += __shfl_xor(s, 8);
            float inv = 1.f / s;
            int t = mf * 16 + crow4 + j;
            lP[t * 72 + 0  + fr] = f2b(e0 * inv);
            lP[t * 72 + 16 + fr] = f2b(e1 * inv);
            lP[t * 72 + 32 + fr] = f2b(e2 * inv);
        }
    }
    __syncthreads();

    f32x4 o[3][8];
#pragma unroll
    for (int mf = 0; mf < 3; ++mf)
#pragma unroll
        for (int nf = 0; nf < 8; ++nf) o[mf][nf] = (f32x4)0.f;

#pragma unroll
    for (int kk = 0; kk < 2; ++kk) {
        s16x8 ap[3];
#pragma unroll
        for (int mf = 0; mf < 3; ++mf) ap[mf] = *(const s16x8*)&lP[(mf * 16 + fr) * 72 + kk * 32 + fk];
#pragma unroll
        for (int nf = 0; nf < 8; ++nf) {
            s16x8 bv = *(const s16x8*)&lVt[(nf * 16 + fr) * 72 + kk * 32 + fk];
#pragma unroll
            for (int mf = 0; mf < 3; ++mf)
                o[mf][nf] = __builtin_amdgcn_mfma_f32_16x16x32_bf16(ap[mf], bv, o[mf][nf], 0, 0, 0);
        }
    }
#pragma unroll
    for (int mf = 0; mf < 3; ++mf)
#pragma unroll
        for (int nf = 0; nf < 8; ++nf)
#pragma unroll
            for (int j = 0; j < 4; ++j) {
                int t = mf * 16 + crow4 + j, d = nf * 16 + fr;
                Qp[(size_t)t * LDQ + d] = f2b(o[mf][nf][j]);
            }
}

// ---------------- combine (memory_bank only) --------------------------------
__global__ void combine_kernel(const u16* __restrict__ RDR, const u16* __restrict__ CDR,
                               const float* __restrict__ srow, const float* __restrict__ scol,
                               const float* __restrict__ emb, float* __restrict__ out_mb) {
    int o = blockIdx.x;
    int k = o / 384, b = (o / 48) & 7, n = o % 48;
    int r2 = (b * 48 + n) * 48 + k;
    float rs = srow[r2], cs = scol[r2];
    float m = fmaxf(rs, cs);
    float e0 = __expf(rs - m), e1 = __expf(cs - m);
    float inv = 1.f / (e0 + e1);
    float w0 = e0 * inv, w1 = e1 * inv;
    const size_t rb = (size_t)r2 * EDIM;
    const size_t ob = (size_t)o * EDIM;
    const size_t eb = ((size_t)(n * 48 + k) * 8 + b) * EDIM;
    for (int e = threadIdx.x; e < EDIM; e += 256) {
        float rv = b2f(RDR[rb + e]);
        float cv = b2f(CDR[rb + e]);
        out_mb[ob + e] = w0 * rv + w1 * cv + emb[eb + e];
    }
}

__global__ void mean_kernel(const float* __restrict__ mb, float* __restrict__ out0) {
    int idx = blockIdx.x * 256 + threadIdx.x;  // 393216
    int n = idx >> 13, b = (idx >> 10) & 7, e = idx & 1023;
    float s = 0.f;
#pragma unroll 8
    for (int k = 0; k < 48; ++k) s += mb[((size_t)(k * 384 + b * 48 + n)) * EDIM + e];
    out0[idx] = s * (1.f / 48.f);
}

// ---------------------------------------------------------------------------
extern "C" void kernel_launch(void* const* d_in, const int* in_sizes, int n_in,
                              void* d_out, int out_size, void* d_ws, size_t ws_size,
                              hipStream_t stream) {
    const float* emb    = (const float*)d_in[0];
    const float* Wq_c   = (const float*)d_in[1];
    const float* bq_c   = (const float*)d_in[2];
    const float* Wk_c   = (const float*)d_in[3];
    const float* bk_c   = (const float*)d_in[4];
    const float* Wv_c   = (const float*)d_in[5];
    const float* bv_c   = (const float*)d_in[6];
    const float* Wo_c   = (const float*)d_in[7];
    const float* bo_c   = (const float*)d_in[8];
    const float* Wq_r   = (const float*)d_in[9];
    const float* bq_r   = (const float*)d_in[10];
    const float* Wk_r   = (const float*)d_in[11];
    const float* bk_r   = (const float*)d_in[12];
    const float* Wv_r   = (const float*)d_in[13];
    const float* bv_r   = (const float*)d_in[14];
    const float* Wo_r   = (const float*)d_in[15];
    const float* bo_r   = (const float*)d_in[16];
    const float* W_gen  = (const float*)d_in[17];
    const float* W_mlp1 = (const float*)d_in[18];
    const float* W_mlp2 = (const float*)d_in[19];

    char* ws = (char*)d_ws;
    size_t off = 0;
    auto alloc = [&](size_t bytes) { char* p = ws + off; off += (bytes + 255) & ~(size_t)255; return p; };
    u16*   WqkvC = (u16*)alloc((size_t)3072 * 1024 * 2);
    u16*   WqkvR = (u16*)alloc((size_t)3072 * 1024 * 2);
    u16*   WoC   = (u16*)alloc((size_t)1024 * 1024 * 2);
    u16*   WoR   = (u16*)alloc((size_t)1024 * 1024 * 2);
    u16*   WgT   = (u16*)alloc((size_t)1024 * 2048 * 2);
    u16*   W1T   = (u16*)alloc((size_t)1024 * 2048 * 2);
    float* bqkvC = (float*)alloc(3072 * 4);
    float* bqkvR = (float*)alloc(3072 * 4);
    u16*   XA    = (u16*)alloc((size_t)MROWS * 1024 * 2);   // gather input; later GEN
    u16*   QKV   = (u16*)alloc((size_t)MROWS * 3072 * 2);   // fused QKV, O in-place
    u16*   CDR   = (u16*)alloc((size_t)MROWS * 1024 * 2);
    u16*   RDR   = (u16*)alloc((size_t)MROWS * 1024 * 2);
    float* score_row = (float*)alloc((size_t)MROWS * 4);
    float* score_col = (float*)alloc((size_t)MROWS * 4);
    (void)ws_size; (void)in_sizes; (void)n_in; (void)out_size;

    dim3 tb(256);
    wconv_kernel<<<dim3(16, 16), tb, 0, stream>>>(Wq_c, WqkvC,                   1024, 1024);
    wconv_kernel<<<dim3(16, 16), tb, 0, stream>>>(Wk_c, WqkvC + 1024 * 1024,     1024, 1024);
    wconv_kernel<<<dim3(16, 16), tb, 0, stream>>>(Wv_c, WqkvC + 2 * 1024 * 1024, 1024, 1024);
    wconv_kernel<<<dim3(16, 16), tb, 0, stream>>>(Wo_c, WoC,                     1024, 1024);
    wconv_kernel<<<dim3(16, 16), tb, 0, stream>>>(Wq_r, WqkvR,                   1024, 1024);
    wconv_kernel<<<dim3(16, 16), tb, 0, stream>>>(Wk_r, WqkvR + 1024 * 1024,     1024, 1024);
    wconv_kernel<<<dim3(16, 16), tb, 0, stream>>>(Wv_r, WqkvR + 2 * 1024 * 1024, 1024, 1024);
    wconv_kernel<<<dim3(16, 16), tb, 0, stream>>>(Wo_r, WoR,                     1024, 1024);
    wconv_kernel<<<dim3(16, 32), tb, 0, stream>>>(W_gen,  WgT, 2048, 1024);
    wconv_kernel<<<dim3(16, 32), tb, 0, stream>>>(W_mlp1, W1T, 2048, 1024);
    bconcat_kernel<<<12, tb, 0, stream>>>(bq_c, bk_c, bv_c, bqkvC);
    bconcat_kernel<<<12, tb, 0, stream>>>(bq_r, bk_r, bv_r, bqkvR);

    gather_kernel<<<MROWS * 512 / 256, tb, 0, stream>>>(emb, XA);
    zero_kernel<<<(2 * MROWS + 255) / 256, tb, 0, stream>>>(score_row, 2 * MROWS);

    float* out = (float*)d_out;
    float* out_mb  = out + 393216;
    float* out_col = out + 393216 + 18874368;
    float* out_row = out + 393216 + 2 * 18874368;

    dim3 tb512(512);
    const int G12 = MT256 * 12, G4 = MT256 * 4, G8m = MT256 * 8;   // 864, 288, 576
    // col QKV (fused, N=3072)
    gemm256_kernel<1024, false, false, false, false, true, 0, false><<<G12, tb512, 0, stream>>>(
        XA, nullptr, nullptr, 1024, WqkvC, bqkvC, QKV, 3072, nullptr, nullptr, nullptr, nullptr);
    attn_kernel<<<384 * 8, 64, 0, stream>>>(QKV);
    // col out-proj: rows (b,k,n) -> CDR rows (b,n,k); f32 out_col
    gemm256_kernel<1024, false, false, true, false, true, 1, false><<<G4, tb512, 0, stream>>>(
        QKV, nullptr, nullptr, 3072, WoC, bo_c, CDR, 1024, out_col, nullptr, nullptr, nullptr);
    // row QKV
    gemm256_kernel<1024, false, false, false, false, true, 0, false><<<G12, tb512, 0, stream>>>(
        CDR, nullptr, nullptr, 1024, WqkvR, bqkvR, QKV, 3072, nullptr, nullptr, nullptr, nullptr);
    attn_kernel<<<384 * 8, 64, 0, stream>>>(QKV);
    // row out-proj: rows (b,n,k) -> RDR; f32 out_row
    gemm256_kernel<1024, false, false, false, false, true, 2, false><<<G4, tb512, 0, stream>>>(
        QKV, nullptr, nullptr, 3072, WoR, bo_r, RDR, 1024, out_row, nullptr, nullptr, nullptr);
    // gen = tanh(concat(RDR,CDR) @ W_gen) -> XA (reused as GEN)
    gemm256_kernel<2048, true, true, false, false, true, 0, false><<<G4, tb512, 0, stream>>>(
        RDR, nullptr, CDR, 1024, WgT, nullptr, XA, 1024, nullptr, nullptr, nullptr, nullptr);
    // scores: merged row+col into one 576-block dispatch (fills CUs better)
    gemm256_kernel<2048, true, true, false, true, false, 0, true><<<G8m, tb512, 0, stream>>>(
        RDR, CDR, XA, 1024, W1T, nullptr, nullptr, 1024, nullptr, W_mlp2, score_row, score_col);

    combine_kernel<<<MROWS, tb, 0, stream>>>(RDR, CDR, score_row, score_col, emb, out_mb);
    mean_kernel<<<393216 / 256, tb, 0, stream>>>(out_mb, out);
}